// Round 1
// baseline (50.063 us; speedup 1.0000x reference)
//
#include <hip/hip_runtime.h>

// One-way Chamfer (L1, K=1): out[0] = mean_i min_j ||x_i - y_j||_1 ; out[1..N] = 0
// N = M = 16384, D = 3, fp32.

#define TPB 256
#define RB 2                       // x-points per thread
#define PTS_PER_BLOCK (TPB * RB)   // 512
#define MAX_MSEG 512               // y-points staged in LDS per block

__global__ __launch_bounds__(TPB) void init_min_kernel(unsigned* __restrict__ minbits, int N) {
    int i = blockIdx.x * TPB + threadIdx.x;
    if (i < N) minbits[i] = 0x7F800000u;  // +inf
}

__global__ __launch_bounds__(TPB) void chamfer_partial_kernel(
    const float* __restrict__ pc1, const float* __restrict__ flow,
    const float* __restrict__ pc2, unsigned* __restrict__ minbits,
    int N, int M, int mseg) {
    __shared__ float4 ys[MAX_MSEG];

    const int t  = threadIdx.x;
    const int y0 = blockIdx.y * mseg;
    const int len = (M - y0 < mseg) ? (M - y0) : mseg;

    // stage this block's pc2 segment into LDS (padded float4 -> ds_read_b128)
    for (int j = t; j < len; j += TPB) {
        const int g = y0 + j;
        ys[j] = make_float4(pc2[3 * g], pc2[3 * g + 1], pc2[3 * g + 2], 0.0f);
    }

    // each thread owns 2 x-points (stride TPB apart for coalescing)
    const int i0 = blockIdx.x * PTS_PER_BLOCK + t;
    const int i1 = i0 + TPB;
    const bool v0 = (i0 < N), v1 = (i1 < N);

    float a0 = 0.f, a1 = 0.f, a2 = 0.f, b0 = 0.f, b1 = 0.f, b2 = 0.f;
    if (v0) {
        a0 = pc1[3 * i0]     + flow[3 * i0];
        a1 = pc1[3 * i0 + 1] + flow[3 * i0 + 1];
        a2 = pc1[3 * i0 + 2] + flow[3 * i0 + 2];
    }
    if (v1) {
        b0 = pc1[3 * i1]     + flow[3 * i1];
        b1 = pc1[3 * i1 + 1] + flow[3 * i1 + 1];
        b2 = pc1[3 * i1 + 2] + flow[3 * i1 + 2];
    }
    __syncthreads();

    // two independent min-chains per point to break the fmin dependency chain
    float mA0 = 1e30f, mA1 = 1e30f, mB0 = 1e30f, mB1 = 1e30f;
    int j = 0;
#pragma unroll 4
    for (; j + 1 < len; j += 2) {
        const float4 ya = ys[j];
        const float4 yb = ys[j + 1];
        mA0 = fminf(mA0, fabsf(a0 - ya.x) + fabsf(a1 - ya.y) + fabsf(a2 - ya.z));
        mB0 = fminf(mB0, fabsf(b0 - ya.x) + fabsf(b1 - ya.y) + fabsf(b2 - ya.z));
        mA1 = fminf(mA1, fabsf(a0 - yb.x) + fabsf(a1 - yb.y) + fabsf(a2 - yb.z));
        mB1 = fminf(mB1, fabsf(b0 - yb.x) + fabsf(b1 - yb.y) + fabsf(b2 - yb.z));
    }
    if (j < len) {
        const float4 ya = ys[j];
        mA0 = fminf(mA0, fabsf(a0 - ya.x) + fabsf(a1 - ya.y) + fabsf(a2 - ya.z));
        mB0 = fminf(mB0, fabsf(b0 - ya.x) + fabsf(b1 - ya.y) + fabsf(b2 - ya.z));
    }
    const float mA = fminf(mA0, mA1);
    const float mB = fminf(mB0, mB1);

    // exact, order-independent combine: uint atomicMin on nonneg float bits
    if (v0) atomicMin(&minbits[i0], __float_as_uint(mA));
    if (v1) atomicMin(&minbits[i1], __float_as_uint(mB));
}

__global__ __launch_bounds__(TPB) void sum_partial_kernel(
    const unsigned* __restrict__ minbits, float* __restrict__ partials, int N) {
    int i = blockIdx.x * TPB + threadIdx.x;
    float v = (i < N) ? __uint_as_float(minbits[i]) : 0.0f;
#pragma unroll
    for (int off = 32; off > 0; off >>= 1) v += __shfl_down(v, off, 64);
    __shared__ float ls[TPB / 64];
    const int wid = threadIdx.x >> 6, lane = threadIdx.x & 63;
    if (lane == 0) ls[wid] = v;
    __syncthreads();
    if (threadIdx.x == 0) {
        float s = 0.0f;
        for (int w = 0; w < TPB / 64; ++w) s += ls[w];
        partials[blockIdx.x] = s;
    }
}

__global__ void final_kernel(const float* __restrict__ partials, int nPart,
                             float* __restrict__ out, float invN) {
    float v = 0.0f;
    for (int i = threadIdx.x; i < nPart; i += 64) v += partials[i];
#pragma unroll
    for (int off = 32; off > 0; off >>= 1) v += __shfl_down(v, off, 64);
    if (threadIdx.x == 0) out[0] = v * invN;
}

extern "C" void kernel_launch(void* const* d_in, const int* in_sizes, int n_in,
                              void* d_out, int out_size, void* d_ws, size_t ws_size,
                              hipStream_t stream) {
    const float* pc1  = (const float*)d_in[0];
    const float* flow = (const float*)d_in[1];
    const float* pc2  = (const float*)d_in[2];
    float* out = (float*)d_out;

    const int N = in_sizes[0] / 3;
    const int M = in_sizes[2] / 3;

    unsigned* minbits = (unsigned*)d_ws;
    float* partials = (float*)((char*)d_ws + (size_t)N * sizeof(unsigned));

    // zero the whole output (freespace_loss part stays zero; out[0] overwritten below)
    hipMemsetAsync(d_out, 0, (size_t)out_size * sizeof(float), stream);

    const int nbN    = (N + PTS_PER_BLOCK - 1) / PTS_PER_BLOCK;   // 32
    const int msplit = (M + MAX_MSEG - 1) / MAX_MSEG;             // 32
    const int mseg   = (M + msplit - 1) / msplit;                 // 512
    const int nPart  = (N + TPB - 1) / TPB;                       // 64

    init_min_kernel<<<(N + TPB - 1) / TPB, TPB, 0, stream>>>(minbits, N);
    chamfer_partial_kernel<<<dim3(nbN, msplit), TPB, 0, stream>>>(pc1, flow, pc2, minbits, N, M, mseg);
    sum_partial_kernel<<<nPart, TPB, 0, stream>>>(minbits, partials, N);
    final_kernel<<<1, 64, 0, stream>>>(partials, nPart, out, 1.0f / (float)N);
}